// Round 4
// baseline (363.127 us; speedup 1.0000x reference)
//
#include <hip/hip_runtime.h>

#define RES 64
#define EPS 1e-6f
#define NBK_MAX 8192

// Fused: one block per (b, k) pair computes the masked-moment reduction and
// writes [F0/d, F1/d, B0/d, B1/d, msum] to ws[bk*8..]. The LAST block to
// finish (device-scope atomic counter) assembles all 21 keypoints per batch.
__global__ __launch_bounds__(256) void reduce_assemble_kernel(
    const float* __restrict__ front_vec,
    const float* __restrict__ front_dis,
    const float* __restrict__ back_vec,
    const float* __restrict__ back_dis,
    const float* __restrict__ ske_mask,
    float* __restrict__ ws,
    unsigned* __restrict__ counter,
    float* __restrict__ out,
    int B)
{
    const int nBK = B * 20;
    const int bk = blockIdx.x;          // b*20 + k
    const int b  = bk / 20;
    const int k  = bk - b * 20;
    const int t  = threadIdx.x;

    // front_vec (B,40,64,64) viewed as (B,20,64,64,2): flat offsets identical.
    const size_t base_v = (size_t)b * (40 * 4096) + (size_t)k * 8192;
    const size_t base_d = (size_t)b * (20 * 4096) + (size_t)k * 4096;

    const float4* __restrict__ fv4 = (const float4*)(front_vec + base_v);
    const float4* __restrict__ bv4 = (const float4*)(back_vec  + base_v);
    const float2* __restrict__ fd2 = (const float2*)(front_dis + base_d);
    const float2* __restrict__ bd2 = (const float2*)(back_dis  + base_d);
    const float2* __restrict__ m2  = (const float2*)(ske_mask  + base_d);

    float s_m = 0.f, s_F0 = 0.f, s_F1 = 0.f, s_B0 = 0.f, s_B1 = 0.f;

    #pragma unroll
    for (int it = 0; it < 8; ++it) {
        const int g  = it * 256 + t;    // pixel-pair index over 2048 pairs
        const int p0 = g * 2;           // first pixel of this pair (even)
        const float y  = (float)(p0 >> 6);   // row (loc component 0)
        const float x0 = (float)(p0 & 63);   // col of first pixel

        const float2 mv = m2[g];
        const float2 fd = fd2[g];
        const float2 bd = bd2[g];
        const float4 fv = fv4[g];       // (v0,v1) for px p0, p0+1
        const float4 bv = bv4[g];

        s_m += mv.x + mv.y;

        // per-element, matching reference: m * (v*d*64 + loc)
        s_F0 += mv.x * fmaf(fv.x * fd.x, 64.f, y)
              + mv.y * fmaf(fv.z * fd.y, 64.f, y);
        s_F1 += mv.x * fmaf(fv.y * fd.x, 64.f, x0)
              + mv.y * fmaf(fv.w * fd.y, 64.f, x0 + 1.f);
        s_B0 += mv.x * fmaf(bv.x * bd.x, 64.f, y)
              + mv.y * fmaf(bv.z * bd.y, 64.f, y);
        s_B1 += mv.x * fmaf(bv.y * bd.x, 64.f, x0)
              + mv.y * fmaf(bv.w * bd.y, 64.f, x0 + 1.f);
    }

    // 64-lane wave reduction
    #pragma unroll
    for (int off = 32; off > 0; off >>= 1) {
        s_m  += __shfl_down(s_m,  off);
        s_F0 += __shfl_down(s_F0, off);
        s_F1 += __shfl_down(s_F1, off);
        s_B0 += __shfl_down(s_B0, off);
        s_B1 += __shfl_down(s_B1, off);
    }

    __shared__ float red[4][5];
    __shared__ bool  is_last;
    const int wave = t >> 6;
    const int lane = t & 63;
    if (lane == 0) {
        red[wave][0] = s_m;
        red[wave][1] = s_F0;
        red[wave][2] = s_F1;
        red[wave][3] = s_B0;
        red[wave][4] = s_B1;
    }
    __syncthreads();
    if (t == 0) {
        float m = 0.f, F0 = 0.f, F1 = 0.f, B0 = 0.f, B1 = 0.f;
        #pragma unroll
        for (int w = 0; w < 4; ++w) {
            m  += red[w][0];
            F0 += red[w][1];
            F1 += red[w][2];
            B0 += red[w][3];
            B1 += red[w][4];
        }
        const float denom = m + EPS;
        float* o = ws + (size_t)bk * 8;
        o[0] = F0 / denom;
        o[1] = F1 / denom;
        o[2] = B0 / denom;
        o[3] = B1 / denom;
        o[4] = m;
        // release our ws record, then signal completion
        __threadfence();
        const unsigned prev = atomicAdd(counter, 1u);
        is_last = (prev == (unsigned)(nBK - 1));
    }
    __syncthreads();
    if (!is_last) return;

    // ---- last block: assemble 21 keypoints for every batch ----
    __threadfence();                    // acquire all other blocks' ws writes
    const int bb = t;                   // one thread per batch element
    if (bb >= B) return;

    float F[20][2], Bk[20][2], ms[20];
    #pragma unroll
    for (int kk = 0; kk < 20; ++kk) {
        const float* w = ws + (size_t)(bb * 20 + kk) * 8;
        F[kk][0]  = w[0];
        F[kk][1]  = w[1];
        Bk[kk][0] = w[2];
        Bk[kk][1] = w[3];
        ms[kk]    = w[4];
    }

    // root keypoint: average of back votes over finger-base channels 0,4,8,12,16
    float r0 = 0.f, r1 = 0.f;
    #pragma unroll
    for (int i = 0; i < 5; ++i) {
        const int c = 4 * i;
        if (ms[c] != 0.f) { r0 += Bk[c][0]; r1 += Bk[c][1]; }
    }

    float* o = out + (size_t)bb * 42;
    o[0] = (r0 / 5.f) * 4.f;
    o[1] = (r1 / 5.f) * 4.f;

    #pragma unroll
    for (int i = 0; i < 5; ++i) {
        const int c = 4 * i;
        float* p = o + 2 * (1 + 4 * i);
        p[0] = F[c + 3][0] * 4.f;
        p[1] = F[c + 3][1] * 4.f;
        p[2] = (F[c + 2][0] + Bk[c + 3][0]) * 2.f;
        p[3] = (F[c + 2][1] + Bk[c + 3][1]) * 2.f;
        p[4] = (F[c + 1][0] + Bk[c + 2][0]) * 2.f;
        p[5] = (F[c + 1][1] + Bk[c + 2][1]) * 2.f;
        p[6] = (F[c + 0][0] + Bk[c + 1][0]) * 2.f;
        p[7] = (F[c + 0][1] + Bk[c + 1][1]) * 2.f;
    }
}

extern "C" void kernel_launch(void* const* d_in, const int* in_sizes, int n_in,
                              void* d_out, int out_size, void* d_ws, size_t ws_size,
                              hipStream_t stream) {
    const float* front_vec = (const float*)d_in[0];
    const float* front_dis = (const float*)d_in[1];
    const float* back_vec  = (const float*)d_in[2];
    const float* back_dis  = (const float*)d_in[3];
    const float* ske_mask  = (const float*)d_in[4];
    float* out = (float*)d_out;
    float* ws  = (float*)d_ws;

    const int B = in_sizes[1] / (20 * RES * RES);   // 256
    const int nBK = B * 20;                          // 5120 blocks

    // counter lives right after the per-bk records in ws
    unsigned* counter = (unsigned*)(ws + (size_t)NBK_MAX * 8);
    hipMemsetAsync(counter, 0, sizeof(unsigned), stream);   // graph-capturable

    reduce_assemble_kernel<<<nBK, 256, 0, stream>>>(
        front_vec, front_dis, back_vec, back_dis, ske_mask, ws, counter, out, B);
}

// Round 5
// 101.995 us; speedup vs baseline: 3.5603x; 3.5603x over previous
//
#include <hip/hip_runtime.h>

#define RES 64
#define EPS 1e-6f

// One block per batch element. 640 threads = 10 waves; wave w reduces
// channels 2w and 2w+1 entirely in-wave (shuffle tree), posts 5 sums per
// channel to LDS. Epilogue: threads 0-19 normalize, thread 0 assembles the
// 21 keypoints. No second dispatch, no atomics, no fences.
__global__ __launch_bounds__(640) void fused_kernel(
    const float* __restrict__ front_vec,
    const float* __restrict__ front_dis,
    const float* __restrict__ back_vec,
    const float* __restrict__ back_dis,
    const float* __restrict__ ske_mask,
    float* __restrict__ out)
{
    const int b    = blockIdx.x;
    const int t    = threadIdx.x;
    const int w    = t >> 6;     // wave 0..9
    const int lane = t & 63;

    __shared__ float red[20][5];              // per-channel {m,F0,F1,B0,B1}
    __shared__ float Fl[20][2], Bl[20][2], msl[20];

    #pragma unroll
    for (int cc = 0; cc < 2; ++cc) {
        const int k = w * 2 + cc;             // this wave's channel

        // front_vec (B,40,64,64) viewed as (B,20,64,64,2): flat offsets identical.
        const size_t base_v = (size_t)b * (40 * 4096) + (size_t)k * 8192;
        const size_t base_d = (size_t)b * (20 * 4096) + (size_t)k * 4096;

        const float4* __restrict__ fv4 = (const float4*)(front_vec + base_v);
        const float4* __restrict__ bv4 = (const float4*)(back_vec  + base_v);
        const float2* __restrict__ fd2 = (const float2*)(front_dis + base_d);
        const float2* __restrict__ bd2 = (const float2*)(back_dis  + base_d);
        const float2* __restrict__ m2  = (const float2*)(ske_mask  + base_d);

        float s_m = 0.f, s_F0 = 0.f, s_F1 = 0.f, s_B0 = 0.f, s_B1 = 0.f;

        // 2048 pixel-pairs per channel / 64 lanes = 32 iterations
        #pragma unroll 4
        for (int i = 0; i < 32; ++i) {
            const int g  = i * 64 + lane;     // pair index (coalesced)
            const int p0 = g * 2;             // first pixel (even)
            const float y  = (float)(p0 >> 6);
            const float x0 = (float)(p0 & 63);

            const float2 mv = m2[g];
            const float2 fd = fd2[g];
            const float2 bd = bd2[g];
            const float4 fv = fv4[g];
            const float4 bv = bv4[g];

            s_m += mv.x + mv.y;

            // per-element, matching reference: m * (v*d*64 + loc)
            s_F0 += mv.x * fmaf(fv.x * fd.x, 64.f, y)
                  + mv.y * fmaf(fv.z * fd.y, 64.f, y);
            s_F1 += mv.x * fmaf(fv.y * fd.x, 64.f, x0)
                  + mv.y * fmaf(fv.w * fd.y, 64.f, x0 + 1.f);
            s_B0 += mv.x * fmaf(bv.x * bd.x, 64.f, y)
                  + mv.y * fmaf(bv.z * bd.y, 64.f, y);
            s_B1 += mv.x * fmaf(bv.y * bd.x, 64.f, x0)
                  + mv.y * fmaf(bv.w * bd.y, 64.f, x0 + 1.f);
        }

        // 64-lane wave reduction
        #pragma unroll
        for (int off = 32; off > 0; off >>= 1) {
            s_m  += __shfl_down(s_m,  off);
            s_F0 += __shfl_down(s_F0, off);
            s_F1 += __shfl_down(s_F1, off);
            s_B0 += __shfl_down(s_B0, off);
            s_B1 += __shfl_down(s_B1, off);
        }

        if (lane == 0) {
            red[k][0] = s_m;
            red[k][1] = s_F0;
            red[k][2] = s_F1;
            red[k][3] = s_B0;
            red[k][4] = s_B1;
        }
    }

    __syncthreads();

    if (t < 20) {
        const float m     = red[t][0];
        const float denom = m + EPS;
        Fl[t][0] = red[t][1] / denom;
        Fl[t][1] = red[t][2] / denom;
        Bl[t][0] = red[t][3] / denom;
        Bl[t][1] = red[t][4] / denom;
        msl[t]   = m;
    }
    __syncthreads();

    if (t == 0) {
        // root keypoint: average back votes over finger-base channels 0,4,8,12,16
        float r0 = 0.f, r1 = 0.f;
        #pragma unroll
        for (int i = 0; i < 5; ++i) {
            const int c = 4 * i;
            if (msl[c] != 0.f) { r0 += Bl[c][0]; r1 += Bl[c][1]; }
        }

        float* o = out + (size_t)b * 42;
        o[0] = (r0 / 5.f) * 4.f;
        o[1] = (r1 / 5.f) * 4.f;

        #pragma unroll
        for (int i = 0; i < 5; ++i) {
            const int c = 4 * i;
            float* p = o + 2 * (1 + 4 * i);
            p[0] = Fl[c + 3][0] * 4.f;
            p[1] = Fl[c + 3][1] * 4.f;
            p[2] = (Fl[c + 2][0] + Bl[c + 3][0]) * 2.f;
            p[3] = (Fl[c + 2][1] + Bl[c + 3][1]) * 2.f;
            p[4] = (Fl[c + 1][0] + Bl[c + 2][0]) * 2.f;
            p[5] = (Fl[c + 1][1] + Bl[c + 2][1]) * 2.f;
            p[6] = (Fl[c + 0][0] + Bl[c + 1][0]) * 2.f;
            p[7] = (Fl[c + 0][1] + Bl[c + 1][1]) * 2.f;
        }
    }
}

extern "C" void kernel_launch(void* const* d_in, const int* in_sizes, int n_in,
                              void* d_out, int out_size, void* d_ws, size_t ws_size,
                              hipStream_t stream) {
    const float* front_vec = (const float*)d_in[0];
    const float* front_dis = (const float*)d_in[1];
    const float* back_vec  = (const float*)d_in[2];
    const float* back_dis  = (const float*)d_in[3];
    const float* ske_mask  = (const float*)d_in[4];
    float* out = (float*)d_out;

    const int B = in_sizes[1] / (20 * RES * RES);   // 256

    fused_kernel<<<B, 640, 0, stream>>>(
        front_vec, front_dis, back_vec, back_dis, ske_mask, out);
}